// Round 7
// baseline (6995.666 us; speedup 1.0000x reference)
//
#include <hip/hip_runtime.h>
#include <cstdint>
#include <cstddef>

static constexpr int NPTS  = 4096;
static constexpr int NB    = 8;
static constexpr int NROWS = NB * NPTS;      // 32768
static constexpr int KNN   = 32;
static constexpr int CAP   = 160;            // survivor list capacity per row

typedef __attribute__((ext_vector_type(8))) short  bf16x8;
typedef __attribute__((ext_vector_type(4))) float  f32x4;

// ---------------- utility: 64-bit shuffles built from 32-bit ----------------
__device__ __forceinline__ unsigned long long shfl_xor_u64(unsigned long long v, int m) {
  int lo = __shfl_xor((int)(unsigned)(v & 0xFFFFFFFFULL), m, 64);
  int hi = __shfl_xor((int)(unsigned)(v >> 32), m, 64);
  return ((unsigned long long)(unsigned)hi << 32) | (unsigned)lo;
}
__device__ __forceinline__ unsigned long long shfl_u64(unsigned long long v, int src) {
  int lo = __shfl((int)(unsigned)(v & 0xFFFFFFFFULL), src, 64);
  int hi = __shfl((int)(unsigned)(v >> 32), src, 64);
  return ((unsigned long long)(unsigned)hi << 32) | (unsigned)lo;
}

// ---------------- squared norms per point ----------------
__global__ __launch_bounds__(256) void sqnorm_kernel(const float* __restrict__ x,
                                                     float* __restrict__ sq, int F) {
  int t = blockIdx.x * 256 + threadIdx.x;
  if (t >= NROWS) return;
  const float* p = x + (size_t)t * F;
  float s = 0.f;
  for (int f = 0; f < F; ++f) s = fmaf(p[f], p[f], s);
  sq[t] = s;
}

// ---------------- fp32 -> bf16 (RNE), element-parallel float4 ----------------
__global__ __launch_bounds__(256) void cvt_kernel(const float* __restrict__ x,
                                                  unsigned short* __restrict__ hi,
                                                  int total4) {
  int t = blockIdx.x * 256 + threadIdx.x;
  if (t >= total4) return;
  float4 v = reinterpret_cast<const float4*>(x)[t];
  ushort4 o;
  unsigned u;
  u = __float_as_uint(v.x); o.x = (unsigned short)((u + 0x7FFFu + ((u >> 16) & 1u)) >> 16);
  u = __float_as_uint(v.y); o.y = (unsigned short)((u + 0x7FFFu + ((u >> 16) & 1u)) >> 16);
  u = __float_as_uint(v.z); o.z = (unsigned short)((u + 0x7FFFu + ((u >> 16) & 1u)) >> 16);
  u = __float_as_uint(v.w); o.w = (unsigned short)((u + 0x7FFFu + ((u >> 16) & 1u)) >> 16);
  reinterpret_cast<ushort4*>(hi)[t] = o;
}

// ---------------- per-batch max of sq ----------------
__global__ __launch_bounds__(256) void batchmax_kernel(const float* __restrict__ sq,
                                                       float* __restrict__ sqmax) {
  int b = blockIdx.x, t = threadIdx.x;
  float m = 0.f;
  for (int i = t; i < NPTS; i += 256) m = fmaxf(m, sq[b * NPTS + i]);
  for (int off = 32; off >= 1; off >>= 1) m = fmaxf(m, __shfl_xor(m, off, 64));
  __shared__ float ls[4];
  if ((t & 63) == 0) ls[t >> 6] = m;
  __syncthreads();
  if (t == 0) sqmax[b] = fmaxf(fmaxf(ls[0], ls[1]), fmaxf(ls[2], ls[3]));
}

// =====================================================================
// Screen (F=64): bf16 hh MFMA approx distances + certified threshold.
// 512 blocks x 256 thr; block owns 64 rows, wave owns 16 (its own A-frag),
// so each staged candidate fragment is read ONCE per wave (4x amortization
// vs R6). Pass 0: per-(lane,reg) top-2 over 256 cands -> tau = max over the
// quad's 16 lanes of 2nd-min (>=32 cands <= tau). Certified error bound:
// |d_bf16hh - d_exact| <= 2^-8*1.01*sqrt(si*sj) <= 0.00198*(si+sqmax);
// eps = 0.004*(si+sqmax)+1e-5 (>=2x margin). tinf = tau + 2*eps admits every
// exact lex-(dist,idx) top-32 member. Pass 1: recompute, append survivors
// via quad-ballot rank (NO LDS atomics). gcnt may exceed CAP (detected).
// =====================================================================
__global__ __launch_bounds__(256, 4)
void knn_screen(const unsigned short* __restrict__ hi,
                const float* __restrict__ sq,
                const float* __restrict__ sqmax,
                int* __restrict__ gcnt,
                unsigned short* __restrict__ glist) {
  constexpr int FPS = 72;   // LDS row stride in shorts (144 B)
  __shared__ __attribute__((aligned(16))) unsigned short chi[128 * FPS];
  __shared__ float csq[128];

  const int t = threadIdx.x, wave = t >> 6, lane = t & 63;
  const int l16 = lane & 15, quad = lane >> 4;
  const int bid = blockIdx.x;
  const int b   = bid & 7;                       // XCD-affine batch
  const int i0w = ((bid >> 3) << 6) + (wave << 4); // this wave's 16 rows
  const size_t base = (size_t)b * NPTS;
  const unsigned short* hib = hi + base * 64;
  const float* sqb = sq + base;
  const float sqm = sqmax[b];

  bf16x8 ahi[2];
#pragma unroll
  for (int kb = 0; kb < 2; ++kb)
    ahi[kb] = *(const bf16x8*)(hib + (size_t)(i0w + l16) * 64 + kb * 32 + quad * 8);
  float sqi4[4];
#pragma unroll
  for (int reg = 0; reg < 4; ++reg) sqi4[reg] = sqb[i0w + quad * 4 + reg];

  float t1[4], t2[4], tinf4[4];
  int cnt4[4] = {0, 0, 0, 0};
#pragma unroll
  for (int reg = 0; reg < 4; ++reg) { t1[reg] = 3.4e38f; t2[reg] = 3.4e38f; tinf4[reg] = 0.f; }

  for (int pass = 0; pass < 2; ++pass) {
    for (int tile = 0; tile < 32; ++tile) {
      __syncthreads();
#pragma unroll
      for (int p = 0; p < 4; ++p) {
        int id = t + p * 256;                 // 0..1023 chunk ids
        int r = id >> 3, c = id & 7;
        *(bf16x8*)&chi[r * FPS + c * 8] =
            *(const bf16x8*)(hib + (size_t)(tile * 128 + r) * 64 + c * 8);
      }
      if (t < 128) csq[t] = sqb[tile * 128 + t];
      __syncthreads();

#pragma unroll 2
      for (int sub = 0; sub < 8; ++sub) {
        const int jl = sub * 16 + l16;
        bf16x8 b0 = *(const bf16x8*)&chi[jl * FPS + quad * 8];
        bf16x8 b1 = *(const bf16x8*)&chi[jl * FPS + 32 + quad * 8];
        f32x4 acc = {0.f, 0.f, 0.f, 0.f};
        acc = __builtin_amdgcn_mfma_f32_16x16x32_bf16(ahi[0], b0, acc, 0, 0, 0);
        acc = __builtin_amdgcn_mfma_f32_16x16x32_bf16(ahi[1], b1, acc, 0, 0, 0);
        const float cs = csq[jl];
        const int jg = tile * 128 + jl;
#pragma unroll
        for (int reg = 0; reg < 4; ++reg) {   // C/D: col=l16, row=quad*4+reg
          float d = fmaf(-2.f, acc[reg], sqi4[reg] + cs);
          if (pass == 0) {
            float lo_ = fminf(d, t1[reg]);
            float hi_ = fmaxf(d, t1[reg]);
            t1[reg] = lo_;
            t2[reg] = fminf(t2[reg], hi_);
          } else {
            bool keep = d <= tinf4[reg];
            unsigned long long mask = __ballot(keep);
            unsigned qm = (unsigned)((mask >> (quad * 16)) & 0xFFFFULL);
            int rank = __popc(qm & ((1u << l16) - 1u));
            if (keep) {
              int pos = cnt4[reg] + rank;
              if (pos < CAP)
                glist[(size_t)(base + i0w + quad * 4 + reg) * CAP + pos] =
                    (unsigned short)jg;
            }
            cnt4[reg] += __popc(qm);
          }
        }
      }
    }
    if (pass == 0) {
#pragma unroll
      for (int reg = 0; reg < 4; ++reg) {
        float v = t2[reg];
#pragma unroll
        for (int off = 1; off < 16; off <<= 1)
          v = fmaxf(v, __shfl_xor(v, off, 64));       // within-quad reduce
        float eps = 0.004f * (sqi4[reg] + sqm) + 1e-5f;
        tinf4[reg] = v + 2.f * eps;
      }
    }
  }

  if (l16 == 0) {
#pragma unroll
    for (int reg = 0; reg < 4; ++reg)
      gcnt[base + i0w + quad * 4 + reg] = cnt4[reg];
  }
}

// =====================================================================
// Rerank: one wave per row. Exact fp32 distances (bit-identical ascending
// c4 fma chain, validated R3-R6) on survivors; exact lex-(dist,idx) top-32
// SET via 44-bit radix-select (order-free: consumer is max-aggregation).
// Overflow (n > CAP) -> full exact scan with validated ballot-insert.
// =====================================================================
__global__ __launch_bounds__(256, 4)
void knn_rerank(const float* __restrict__ x, const float* __restrict__ sq,
                const int* __restrict__ gcnt,
                const unsigned short* __restrict__ glist,
                unsigned short* __restrict__ idx_out) {
  const int t = threadIdx.x, wave = t >> 6, lane = t & 63;
  const int row = blockIdx.x * 4 + wave;      // 0..32767
  const int b = row >> 12;
  const int i = row & (NPTS - 1);
  const float* xb  = x + (size_t)b * NPTS * 64;
  const float* sqb = sq + ((size_t)b << 12);
  const float sqi = sqb[i];

  float4 q[16];
#pragma unroll
  for (int c4 = 0; c4 < 16; ++c4)
    q[c4] = *(const float4*)(xb + (size_t)i * 64 + c4 * 4);

  const int n = gcnt[row];

  if (n <= CAP) {
    unsigned long long vk[3];
#pragma unroll
    for (int s = 0; s < 3; ++s) {
      int li = s * 64 + lane;
      unsigned long long v = 0xFFFFFFFFFFFULL;        // sentinel > any real
      if (li < n) {
        int j = glist[(size_t)row * CAP + li];
        const float4* xj = (const float4*)(xb + (size_t)j * 64);
        float dot = 0.f;
#pragma unroll
        for (int c4 = 0; c4 < 16; ++c4) {
          float4 c = xj[c4];
          dot = fmaf(q[c4].x, c.x, dot);
          dot = fmaf(q[c4].y, c.y, dot);
          dot = fmaf(q[c4].z, c.z, dot);
          dot = fmaf(q[c4].w, c.w, dot);
        }
        float d = fmaf(-2.f, dot, sqi + sqb[j]);
        unsigned u  = __float_as_uint(d);
        unsigned ck = (u & 0x80000000u) ? ~u : (u | 0x80000000u);
        v = ((unsigned long long)ck << 12) | (unsigned)j;
      }
      vk[s] = v;
    }
    // radix-select: prefix ends as the exact 32nd-smallest value (distinct)
    unsigned long long prefix = 0;
    int need = 32;
    for (int bit = 43; bit >= 0; --bit) {
      unsigned long long hm = (bit == 43) ? 0ULL
          : (~((1ULL << (bit + 1)) - 1ULL) & 0xFFFFFFFFFFFULL);
      int cnt0 = 0;
#pragma unroll
      for (int s = 0; s < 3; ++s) {
        bool a = ((vk[s] ^ prefix) & hm) == 0ULL;
        bool z = ((vk[s] >> bit) & 1ULL) == 0ULL;
        cnt0 += (int)__popcll(__ballot(a && z));
      }
      if (cnt0 < need) { need -= cnt0; prefix |= 1ULL << bit; }
    }
    int prev = 0;
#pragma unroll
    for (int s = 0; s < 3; ++s) {
      bool sel = vk[s] <= prefix;
      unsigned long long m = __ballot(sel);
      int rank = (int)__popcll(m & ((1ULL << lane) - 1ULL));
      if (sel)
        idx_out[(size_t)row * KNN + prev + rank] =
            (unsigned short)(vk[s] & 0xFFFULL);
      prev += (int)__popcll(m);
    }
  } else {
    // fallback: exact full scan, validated ballot-insert
    unsigned long long ent = (0xFFFFFFFFFFFULL << 5) | (unsigned long long)(lane & 31);
    unsigned long long M   = (0xFFFFFFFFFFFULL << 5) | 31ULL;
    for (int c0 = 0; c0 < NPTS; c0 += 64) {
      const int j = c0 + lane;
      const float4* xj = (const float4*)(xb + (size_t)j * 64);
      float dot = 0.f;
#pragma unroll
      for (int c4 = 0; c4 < 16; ++c4) {
        float4 c = xj[c4];
        dot = fmaf(q[c4].x, c.x, dot);
        dot = fmaf(q[c4].y, c.y, dot);
        dot = fmaf(q[c4].z, c.z, dot);
        dot = fmaf(q[c4].w, c.w, dot);
      }
      float d = fmaf(-2.f, dot, sqi + sqb[j]);
      unsigned u  = __float_as_uint(d);
      unsigned ck = (u & 0x80000000u) ? ~u : (u | 0x80000000u);
      unsigned long long cq = ((unsigned long long)ck << 12) | (unsigned)j;
      unsigned long long mask = __ballot(cq < (M >> 5));
      while (mask) {
        const int src = __builtin_ctzll(mask);
        mask &= mask - 1;
        const unsigned long long bq = shfl_u64(cq, src);
        if (bq < (M >> 5)) {
          const unsigned slot = (unsigned)(M & 31ULL);
          if ((unsigned)(lane & 31) == slot) ent = (bq << 5) | slot;
          unsigned long long v = ent;
#pragma unroll
          for (int off = 16; off >= 1; off >>= 1) {
            unsigned long long w2 = shfl_xor_u64(v, off);
            v = (v > w2) ? v : w2;
          }
          M = v;
        }
      }
    }
    if (lane < 32)
      idx_out[(size_t)row * KNN + lane] =
          (unsigned short)((ent >> 5) & 0xFFFULL);
  }
}

// ---------------- F=3 kNN (validated two-pass VALU path) ----------------
template <int F>
__global__ __launch_bounds__(256, 2) void knn_tiled(const float* __restrict__ x,
                                                    const float* __restrict__ sq,
                                                    unsigned short* __restrict__ idx_out) {
  constexpr int FP = 4;
  constexpr int TC = 256;
  constexpr int RPB = 32;
  constexpr int RPW = 8;

  __shared__ __attribute__((aligned(16))) float qv[RPB][FP];
  __shared__ float qsq[RPB];
  __shared__ __attribute__((aligned(16))) float ct[TC][FP];
  __shared__ float csq[TC];

  const int t    = threadIdx.x;
  const int wave = t >> 6;
  const int lane = t & 63;
  const int rowbase = blockIdx.x << 5;
  const int b     = rowbase >> 12;
  const int ibase = rowbase & (NPTS - 1);
  const float* xb  = x + (size_t)b * NPTS * F;
  const float* sqb = sq + (b << 12);

  if (t < RPB) {
    qv[t][0] = xb[(size_t)(ibase + t) * 3 + 0];
    qv[t][1] = xb[(size_t)(ibase + t) * 3 + 1];
    qv[t][2] = xb[(size_t)(ibase + t) * 3 + 2];
    qv[t][3] = 0.f;
    qsq[t] = sqb[ibase + t];
  }
  __syncthreads();

  const int r0 = wave << 3;
  float sqi[RPW];
#pragma unroll
  for (int rr = 0; rr < RPW; ++rr) sqi[rr] = qsq[r0 + rr];

  unsigned mn[RPW];
#pragma unroll
  for (int rr = 0; rr < RPW; ++rr) mn[rr] = 0xFFFFFFFFu;

  for (int tile = 0; tile < NPTS / TC; ++tile) {
    __syncthreads();
    {
      int jg = tile * TC + t;
      ct[t][0] = xb[(size_t)jg * 3 + 0];
      ct[t][1] = xb[(size_t)jg * 3 + 1];
      ct[t][2] = xb[(size_t)jg * 3 + 2];
      ct[t][3] = 0.f;
      csq[t] = sqb[jg];
    }
    __syncthreads();

    float4 c0 = *reinterpret_cast<const float4*>(&ct[lane][0]);
    float4 c1 = *reinterpret_cast<const float4*>(&ct[lane + 64][0]);
    float4 c2 = *reinterpret_cast<const float4*>(&ct[lane + 128][0]);
    float4 c3 = *reinterpret_cast<const float4*>(&ct[lane + 192][0]);
    float cs[4];
#pragma unroll
    for (int s = 0; s < 4; ++s) cs[s] = csq[lane + 64 * s];

#pragma unroll
    for (int rr = 0; rr < RPW; ++rr) {
      float4 q = *reinterpret_cast<const float4*>(&qv[r0 + rr][0]);
      float dd[4];
      dd[0] = fmaf(q.z, c0.z, fmaf(q.y, c0.y, q.x * c0.x));
      dd[1] = fmaf(q.z, c1.z, fmaf(q.y, c1.y, q.x * c1.x));
      dd[2] = fmaf(q.z, c2.z, fmaf(q.y, c2.y, q.x * c2.x));
      dd[3] = fmaf(q.z, c3.z, fmaf(q.y, c3.y, q.x * c3.x));
#pragma unroll
      for (int s = 0; s < 4; ++s) {
        float d = fmaf(-2.f, dd[s], sqi[rr] + cs[s]);
        unsigned u  = __float_as_uint(d);
        unsigned ck = (u & 0x80000000u) ? ~u : (u | 0x80000000u);
        mn[rr] = ck < mn[rr] ? ck : mn[rr];
      }
    }
  }

  unsigned tau[RPW];
#pragma unroll
  for (int rr = 0; rr < RPW; ++rr) {
    const unsigned v = mn[rr];
    unsigned prefix = 0;
    int need = 32;
    int act = 1;
    for (int bit = 31; bit >= 0; --bit) {
      const unsigned bv = (v >> bit) & 1u;
      unsigned long long m0 = __ballot(act && (bv == 0u));
      int c0n = (int)__popcll(m0);
      if (c0n >= need) {
        act = act && (bv == 0u);
      } else {
        need -= c0n;
        act = act && (bv == 1u);
        prefix |= (1u << bit);
      }
    }
    tau[rr] = prefix;
  }

  unsigned long long ent[RPW], M[RPW];
#pragma unroll
  for (int rr = 0; rr < RPW; ++rr) {
    ent[rr] = (0xFFFFFFFFFFFULL << 5) | (unsigned long long)(lane & 31);
    M[rr]   = (0xFFFFFFFFFFFULL << 5) | 31ULL;
  }

  for (int tile = 0; tile < NPTS / TC; ++tile) {
    __syncthreads();
    {
      int jg = tile * TC + t;
      ct[t][0] = xb[(size_t)jg * 3 + 0];
      ct[t][1] = xb[(size_t)jg * 3 + 1];
      ct[t][2] = xb[(size_t)jg * 3 + 2];
      ct[t][3] = 0.f;
      csq[t] = sqb[jg];
    }
    __syncthreads();

    float4 c0 = *reinterpret_cast<const float4*>(&ct[lane][0]);
    float4 c1 = *reinterpret_cast<const float4*>(&ct[lane + 64][0]);
    float4 c2 = *reinterpret_cast<const float4*>(&ct[lane + 128][0]);
    float4 c3 = *reinterpret_cast<const float4*>(&ct[lane + 192][0]);
    float cs[4];
#pragma unroll
    for (int s = 0; s < 4; ++s) cs[s] = csq[lane + 64 * s];

#pragma unroll
    for (int rr = 0; rr < RPW; ++rr) {
      float4 q = *reinterpret_cast<const float4*>(&qv[r0 + rr][0]);
      float dd[4];
      dd[0] = fmaf(q.z, c0.z, fmaf(q.y, c0.y, q.x * c0.x));
      dd[1] = fmaf(q.z, c1.z, fmaf(q.y, c1.y, q.x * c1.x));
      dd[2] = fmaf(q.z, c2.z, fmaf(q.y, c2.y, q.x * c2.x));
      dd[3] = fmaf(q.z, c3.z, fmaf(q.y, c3.y, q.x * c3.x));
#pragma unroll
      for (int s = 0; s < 4; ++s) {
        float d = fmaf(-2.f, dd[s], sqi[rr] + cs[s]);
        unsigned u  = __float_as_uint(d);
        unsigned ck = (u & 0x80000000u) ? ~u : (u | 0x80000000u);
        unsigned long long mask = __ballot(ck <= tau[rr]);
        while (mask) {
          const int src = __builtin_ctzll(mask);
          mask &= mask - 1;
          const unsigned bk   = (unsigned)__shfl((int)ck, src, 64);
          const unsigned bidx = (unsigned)(tile * TC + s * 64 + src);
          const unsigned long long bq = ((unsigned long long)bk << 12) | bidx;
          if (bq < (M[rr] >> 5)) {
            const unsigned slot = (unsigned)(M[rr] & 31ULL);
            if ((unsigned)(lane & 31) == slot)
              ent[rr] = (bq << 5) | slot;
            unsigned long long v = ent[rr];
#pragma unroll
            for (int off = 16; off >= 1; off >>= 1) {
              unsigned long long w2 = shfl_xor_u64(v, off);
              v = (v > w2) ? v : w2;
            }
            M[rr] = v;
          }
        }
      }
    }
  }

  if (lane < 32) {
#pragma unroll
    for (int rr = 0; rr < RPW; ++rr)
      idx_out[((rowbase + r0 + rr) << 5) + lane] =
          (unsigned short)((ent[rr] >> 5) & 0xFFFULL);
  }
}

// ---------------- per-node P = x.Wbot ; C = x.(Wtop-Wbot) + b ----------------
__global__ __launch_bounds__(256) void mlp_pc_kernel(const float* __restrict__ xin,
                                                     const float* __restrict__ W,
                                                     const float* __restrict__ bias,
                                                     float* __restrict__ P,
                                                     float* C,
                                                     int F, int O, int total) {
  int t = blockIdx.x * 256 + threadIdx.x;
  if (t >= total) return;
  int n = t / O, o = t % O;
  const float* xr = xin + (size_t)n * F;
  const float* Wt = W + o;
  const float* Wb = W + (size_t)F * O + o;
  float p = 0.f, c = 0.f;
  for (int f = 0; f < F; ++f) {
    float a  = xr[f];
    float wt = Wt[(size_t)f * O];
    float wb = Wb[(size_t)f * O];
    p = fmaf(a, wb, p);
    c = fmaf(a, wt - wb, c);
  }
  P[t] = p;
  C[t] = c + bias[o];
}

// ---------------- h[t] (pre-filled with C) += max_k P[idx_k] ----------------
__global__ __launch_bounds__(256) void aggregate_kernel(const unsigned short* __restrict__ idx,
                                                        const float* __restrict__ P,
                                                        float* h, int O, int total) {
  int t = blockIdx.x * 256 + threadIdx.x;
  if (t >= total) return;
  int n = t / O, o = t % O;
  const unsigned short* ix = idx + (size_t)n * KNN;
  const int rowbase = (n >> 12) << 12;
  float m = -3.402823466e+38f;
  for (int k = 0; k < KNN; ++k) {
    int jg = rowbase + ix[k];
    float v = P[(size_t)jg * O + o];
    m = fmaxf(m, v);
  }
  h[t] = h[t] + m;
}

// ---------------- BN stats over relu(h): mean + invstd per channel ----------
__global__ __launch_bounds__(256) void bn_stats_kernel(const float* __restrict__ h,
                                                       float* __restrict__ stats) {
  const int c = blockIdx.x;
  const int t = threadIdx.x;
  double s = 0.0, s2 = 0.0;
  for (int n = t; n < NROWS; n += 256) {
    float v = h[(size_t)n * 64 + c];
    v = v > 0.f ? v : 0.f;
    s += v;
    s2 += (double)v * v;
  }
  __shared__ double ls[256], ls2[256];
  ls[t] = s; ls2[t] = s2;
  __syncthreads();
  for (int st = 128; st; st >>= 1) {
    if (t < st) { ls[t] += ls[t + st]; ls2[t] += ls2[t + st]; }
    __syncthreads();
  }
  if (t == 0) {
    double mean = ls[0] / (double)NROWS;
    double var  = ls2[0] / (double)NROWS - mean * mean;
    stats[c]      = (float)mean;
    stats[64 + c] = (float)(1.0 / sqrt(var + 1e-5));
  }
}

// ---------------- apply: out = (relu(h)-mean)*invstd*g + be ----------------
__global__ __launch_bounds__(256) void bn_apply_kernel(const float* h,
                                                       const float* __restrict__ stats,
                                                       const float* __restrict__ g,
                                                       const float* __restrict__ be,
                                                       float* out, int total) {
  int t = blockIdx.x * 256 + threadIdx.x;
  if (t >= total) return;
  int ch = t & 63;
  float v = fmaxf(h[t], 0.f);
  out[t] = (v - stats[ch]) * stats[64 + ch] * g[ch] + be[ch];
}

// ---------------- write h3 to out + per-block loss partials ----------------
__global__ __launch_bounds__(256) void final_kernel(const float* __restrict__ h3,
                                                    const float* __restrict__ target,
                                                    float* __restrict__ out,
                                                    double* __restrict__ partial) {
  double s = 0.0;
  for (int t = blockIdx.x * 256 + threadIdx.x; t < NROWS * 3; t += 256 * 256) {
    float v = h3[t];
    out[t] = v;
    float d = v - target[t];
    s += (double)d * d;
  }
  __shared__ double ls[256];
  int t = threadIdx.x;
  ls[t] = s;
  __syncthreads();
  for (int st = 128; st; st >>= 1) {
    if (t < st) ls[t] += ls[t + st];
    __syncthreads();
  }
  if (t == 0) partial[blockIdx.x] = ls[0];
}

__global__ __launch_bounds__(256) void loss_kernel(const double* __restrict__ partial,
                                                   float* __restrict__ out) {
  int t = threadIdx.x;
  __shared__ double ls[256];
  ls[t] = partial[t];
  __syncthreads();
  for (int st = 128; st; st >>= 1) {
    if (t < st) ls[t] += ls[t + st];
    __syncthreads();
  }
  if (t == 0) out[NROWS * 3] = (float)(ls[0] / (double)(NROWS * 3));
}

// ---------------- driver ----------------
extern "C" void kernel_launch(void* const* d_in, const int* in_sizes, int n_in,
                              void* d_out, int out_size, void* d_ws, size_t ws_size,
                              hipStream_t stream) {
  const float* x   = (const float*)d_in[0];
  const float* tgt = (const float*)d_in[1];
  const float* W1  = (const float*)d_in[2];
  const float* b1  = (const float*)d_in[3];
  const float* g1  = (const float*)d_in[4];
  const float* be1 = (const float*)d_in[5];
  const float* W2  = (const float*)d_in[6];
  const float* b2  = (const float*)d_in[7];
  const float* g2  = (const float*)d_in[8];
  const float* be2 = (const float*)d_in[9];
  const float* W3  = (const float*)d_in[10];
  const float* b3  = (const float*)d_in[11];
  float* out = (float*)d_out;

  char* ws = (char*)d_ws;
  size_t off = 0;
  float* sq    = (float*)(ws + off); off += (size_t)NROWS * 4;           // 128 KB
  unsigned short* idxb = (unsigned short*)(ws + off); off += (size_t)NROWS * KNN * 2; // 2 MB
  float* P     = (float*)(ws + off); off += (size_t)NROWS * 64 * 4;      // 8 MB
  float* CA    = (float*)(ws + off); off += (size_t)NROWS * 64 * 4;      // 8 MB
  float* CB    = (float*)(ws + off); off += (size_t)NROWS * 64 * 4;      // 8 MB
  int*   gcnt  = (int*)(ws + off);   off += (size_t)NROWS * 4;           // 128 KB
  unsigned short* glist = (unsigned short*)(ws + off); off += (size_t)NROWS * CAP * 2; // 10 MB
  float* stats = (float*)(ws + off); off += 256 * 4;
  float* sqmax = (float*)(ws + off); off += 64;
  double* part = (double*)(ws + off); off += 256 * 8;

  // hi (bf16, 4 MB) aliases P: P is dead during screen/rerank, written after.
  unsigned short* hib = (unsigned short*)P;

  const int T64 = NROWS * 64;
  const int T3  = NROWS * 3;

  // ---- layer 1 (F=3 -> 64), VALU kNN ----
  sqnorm_kernel<<<NROWS / 256, 256, 0, stream>>>(x, sq, 3);
  knn_tiled<3><<<NROWS / 32, 256, 0, stream>>>(x, sq, idxb);
  mlp_pc_kernel<<<T64 / 256, 256, 0, stream>>>(x, W1, b1, P, CA, 3, 64, T64);
  aggregate_kernel<<<T64 / 256, 256, 0, stream>>>(idxb, P, CA, 64, T64);
  bn_stats_kernel<<<64, 256, 0, stream>>>(CA, stats);
  bn_apply_kernel<<<T64 / 256, 256, 0, stream>>>(CA, stats, g1, be1, CA, T64);

  // ---- layer 2 (F=64 -> 64), MFMA screen + exact rerank ----
  sqnorm_kernel<<<NROWS / 256, 256, 0, stream>>>(CA, sq, 64);
  cvt_kernel<<<T64 / 4 / 256, 256, 0, stream>>>(CA, hib, T64 / 4);
  batchmax_kernel<<<NB, 256, 0, stream>>>(sq, sqmax);
  knn_screen<<<512, 256, 0, stream>>>(hib, sq, sqmax, gcnt, glist);
  knn_rerank<<<NROWS / 4, 256, 0, stream>>>(CA, sq, gcnt, glist, idxb);
  mlp_pc_kernel<<<T64 / 256, 256, 0, stream>>>(CA, W2, b2, P, CB, 64, 64, T64);
  aggregate_kernel<<<T64 / 256, 256, 0, stream>>>(idxb, P, CB, 64, T64);
  bn_stats_kernel<<<64, 256, 0, stream>>>(CB, stats);
  bn_apply_kernel<<<T64 / 256, 256, 0, stream>>>(CB, stats, g2, be2, CB, T64);

  // ---- layer 3 (F=64 -> 3), MFMA screen + exact rerank ----
  sqnorm_kernel<<<NROWS / 256, 256, 0, stream>>>(CB, sq, 64);
  cvt_kernel<<<T64 / 4 / 256, 256, 0, stream>>>(CB, hib, T64 / 4);
  batchmax_kernel<<<NB, 256, 0, stream>>>(sq, sqmax);
  knn_screen<<<512, 256, 0, stream>>>(hib, sq, sqmax, gcnt, glist);
  knn_rerank<<<NROWS / 4, 256, 0, stream>>>(CB, sq, gcnt, glist, idxb);
  mlp_pc_kernel<<<T3 / 256, 256, 0, stream>>>(CB, W3, b3, P, CA, 64, 3, T3);
  aggregate_kernel<<<T3 / 256, 256, 0, stream>>>(idxb, P, CA, 3, T3);

  // ---- output + loss ----
  final_kernel<<<256, 256, 0, stream>>>(CA, tgt, out, part);
  loss_kernel<<<1, 256, 0, stream>>>(part, out);
}

// Round 8
// 1649.156 us; speedup vs baseline: 4.2420x; 4.2420x over previous
//
#include <hip/hip_runtime.h>
#include <cstdint>
#include <cstddef>

static constexpr int NPTS  = 4096;
static constexpr int NB    = 8;
static constexpr int NROWS = NB * NPTS;      // 32768
static constexpr int KNN   = 32;
static constexpr int CAP   = 192;            // survivor list capacity per row (3x64)

typedef __attribute__((ext_vector_type(8))) short  bf16x8;
typedef __attribute__((ext_vector_type(4))) float  f32x4;

// ---------------- utility: 64-bit shuffles built from 32-bit ----------------
__device__ __forceinline__ unsigned long long shfl_xor_u64(unsigned long long v, int m) {
  int lo = __shfl_xor((int)(unsigned)(v & 0xFFFFFFFFULL), m, 64);
  int hi = __shfl_xor((int)(unsigned)(v >> 32), m, 64);
  return ((unsigned long long)(unsigned)hi << 32) | (unsigned)lo;
}
__device__ __forceinline__ unsigned long long shfl_u64(unsigned long long v, int src) {
  int lo = __shfl((int)(unsigned)(v & 0xFFFFFFFFULL), src, 64);
  int hi = __shfl((int)(unsigned)(v >> 32), src, 64);
  return ((unsigned long long)(unsigned)hi << 32) | (unsigned)lo;
}

// ---------------- squared norms per point ----------------
__global__ __launch_bounds__(256) void sqnorm_kernel(const float* __restrict__ x,
                                                     float* __restrict__ sq, int F) {
  int t = blockIdx.x * 256 + threadIdx.x;
  if (t >= NROWS) return;
  const float* p = x + (size_t)t * F;
  float s = 0.f;
  for (int f = 0; f < F; ++f) s = fmaf(p[f], p[f], s);
  sq[t] = s;
}

// ---------------- split fp32 -> bf16 hi + bf16 lo (RNE) ----------------
__global__ __launch_bounds__(256) void split_kernel(const float* __restrict__ x,
                                                    unsigned short* __restrict__ hi,
                                                    unsigned short* __restrict__ lo,
                                                    int total) {
  int t = blockIdx.x * 256 + threadIdx.x;
  if (t >= total) return;
  float v = x[t];
  unsigned u = __float_as_uint(v);
  unsigned h = (u + 0x7FFFu + ((u >> 16) & 1u)) >> 16;
  float hf = __uint_as_float(h << 16);
  float r = v - hf;
  unsigned ur = __float_as_uint(r);
  unsigned l = (ur + 0x7FFFu + ((ur >> 16) & 1u)) >> 16;
  hi[t] = (unsigned short)h;
  lo[t] = (unsigned short)l;
}

// ---------------- per-batch max of sq ----------------
__global__ __launch_bounds__(256) void batchmax_kernel(const float* __restrict__ sq,
                                                       float* __restrict__ sqmax) {
  int b = blockIdx.x, t = threadIdx.x;
  float m = 0.f;
  for (int i = t; i < NPTS; i += 256) m = fmaxf(m, sq[b * NPTS + i]);
  for (int off = 32; off >= 1; off >>= 1) m = fmaxf(m, __shfl_xor(m, off, 64));
  __shared__ float ls[4];
  if ((t & 63) == 0) ls[t >> 6] = m;
  __syncthreads();
  if (t == 0) sqmax[b] = fmaxf(fmaxf(ls[0], ls[1]), fmaxf(ls[2], ls[3]));
}

// =====================================================================
// Screen (F=64): 3-term bf16 hi/lo MFMA approx distances (hh+hl+lh, the
// R6-validated product and accumulation order) + certified threshold
// eps = 6e-5*(si+sqmax)+1e-5 (R6-validated >=2x margin over the 2^-18
// cross-term + fp32-accum bound). Structure from R7: 512 blocks x 256 thr,
// block owns 64 rows, wave owns its own 16 (A-frags read once), candidate
// tile of 128 staged in LDS (hi+lo). Pass 0: per-(lane,reg) top-2 over the
// lane's 256 cands -> tau = max over quad's 16 lanes of 2nd-min (>=32
// cands <= tau); tinf = tau + 2*eps admits every exact lex-(dist,idx)
// top-32 member. Pass 1: recompute, append survivors via quad-ballot rank
// (no LDS atomics). gcnt may exceed CAP (overflow detected in rerank).
// =====================================================================
__global__ __launch_bounds__(256, 4)
void knn_screen(const unsigned short* __restrict__ hi,
                const unsigned short* __restrict__ lo,
                const float* __restrict__ sq,
                const float* __restrict__ sqmax,
                int* __restrict__ gcnt,
                unsigned short* __restrict__ glist) {
  constexpr int FPS = 72;   // LDS row stride in shorts (144 B)
  __shared__ __attribute__((aligned(16))) unsigned short chi[128 * FPS];
  __shared__ __attribute__((aligned(16))) unsigned short clo[128 * FPS];
  __shared__ float csq[128];

  const int t = threadIdx.x, wave = t >> 6, lane = t & 63;
  const int l16 = lane & 15, quad = lane >> 4;
  const int bid = blockIdx.x;
  const int b   = bid & 7;                         // XCD-affine batch
  const int i0w = ((bid >> 3) << 6) + (wave << 4); // this wave's 16 rows
  const size_t base = (size_t)b * NPTS;
  const unsigned short* hib = hi + base * 64;
  const unsigned short* lob = lo + base * 64;
  const float* sqb = sq + base;
  const float sqm = sqmax[b];

  bf16x8 ahi[2], alo[2];
#pragma unroll
  for (int kb = 0; kb < 2; ++kb) {
    ahi[kb] = *(const bf16x8*)(hib + (size_t)(i0w + l16) * 64 + kb * 32 + quad * 8);
    alo[kb] = *(const bf16x8*)(lob + (size_t)(i0w + l16) * 64 + kb * 32 + quad * 8);
  }
  float sqi4[4];
#pragma unroll
  for (int reg = 0; reg < 4; ++reg) sqi4[reg] = sqb[i0w + quad * 4 + reg];

  float t1[4], t2[4], tinf4[4];
  int cnt4[4] = {0, 0, 0, 0};
#pragma unroll
  for (int reg = 0; reg < 4; ++reg) { t1[reg] = 3.4e38f; t2[reg] = 3.4e38f; tinf4[reg] = 0.f; }

  for (int pass = 0; pass < 2; ++pass) {
    for (int tile = 0; tile < 32; ++tile) {
      __syncthreads();
#pragma unroll
      for (int p = 0; p < 4; ++p) {
        int id = t + p * 256;                 // 0..1023 chunk ids
        int r = id >> 3, c = id & 7;
        *(bf16x8*)&chi[r * FPS + c * 8] =
            *(const bf16x8*)(hib + (size_t)(tile * 128 + r) * 64 + c * 8);
        *(bf16x8*)&clo[r * FPS + c * 8] =
            *(const bf16x8*)(lob + (size_t)(tile * 128 + r) * 64 + c * 8);
      }
      if (t < 128) csq[t] = sqb[tile * 128 + t];
      __syncthreads();

#pragma unroll 2
      for (int sub = 0; sub < 8; ++sub) {
        const int jl = sub * 16 + l16;
        bf16x8 bh0 = *(const bf16x8*)&chi[jl * FPS + quad * 8];
        bf16x8 bh1 = *(const bf16x8*)&chi[jl * FPS + 32 + quad * 8];
        bf16x8 bl0 = *(const bf16x8*)&clo[jl * FPS + quad * 8];
        bf16x8 bl1 = *(const bf16x8*)&clo[jl * FPS + 32 + quad * 8];
        f32x4 acc = {0.f, 0.f, 0.f, 0.f};
        acc = __builtin_amdgcn_mfma_f32_16x16x32_bf16(ahi[0], bh0, acc, 0, 0, 0);
        acc = __builtin_amdgcn_mfma_f32_16x16x32_bf16(ahi[1], bh1, acc, 0, 0, 0);
        acc = __builtin_amdgcn_mfma_f32_16x16x32_bf16(ahi[0], bl0, acc, 0, 0, 0);
        acc = __builtin_amdgcn_mfma_f32_16x16x32_bf16(ahi[1], bl1, acc, 0, 0, 0);
        acc = __builtin_amdgcn_mfma_f32_16x16x32_bf16(alo[0], bh0, acc, 0, 0, 0);
        acc = __builtin_amdgcn_mfma_f32_16x16x32_bf16(alo[1], bh1, acc, 0, 0, 0);
        const float cs = csq[jl];
        const int jg = tile * 128 + jl;
#pragma unroll
        for (int reg = 0; reg < 4; ++reg) {   // C/D: col=l16, row=quad*4+reg
          float d = fmaf(-2.f, acc[reg], sqi4[reg] + cs);
          if (pass == 0) {
            float lo_ = fminf(d, t1[reg]);
            float hi_ = fmaxf(d, t1[reg]);
            t1[reg] = lo_;
            t2[reg] = fminf(t2[reg], hi_);
          } else {
            bool keep = d <= tinf4[reg];
            unsigned long long mask = __ballot(keep);
            unsigned qm = (unsigned)((mask >> (quad * 16)) & 0xFFFFULL);
            int rank = __popc(qm & ((1u << l16) - 1u));
            if (keep) {
              int pos = cnt4[reg] + rank;
              if (pos < CAP)
                glist[(size_t)(base + i0w + quad * 4 + reg) * CAP + pos] =
                    (unsigned short)jg;
            }
            cnt4[reg] += __popc(qm);
          }
        }
      }
    }
    if (pass == 0) {
#pragma unroll
      for (int reg = 0; reg < 4; ++reg) {
        float v = t2[reg];
#pragma unroll
        for (int off = 1; off < 16; off <<= 1)
          v = fmaxf(v, __shfl_xor(v, off, 64));       // within-quad reduce
        float eps = 6e-5f * (sqi4[reg] + sqm) + 1e-5f;
        tinf4[reg] = v + 2.f * eps;
      }
    }
  }

  if (l16 == 0) {
#pragma unroll
    for (int reg = 0; reg < 4; ++reg)
      gcnt[base + i0w + quad * 4 + reg] = cnt4[reg];
  }
}

// =====================================================================
// Rerank: one wave per row. Exact fp32 distances (bit-identical ascending
// c4 fma chain, validated R3-R7) on survivors; exact lex-(dist,idx) top-32
// SET via 44-bit radix-select (order-free: consumer is max-aggregation).
// Overflow (n > CAP) -> full exact scan with validated ballot-insert
// (rare with the tight 3-term eps).
// =====================================================================
__global__ __launch_bounds__(256, 4)
void knn_rerank(const float* __restrict__ x, const float* __restrict__ sq,
                const int* __restrict__ gcnt,
                const unsigned short* __restrict__ glist,
                unsigned short* __restrict__ idx_out) {
  const int t = threadIdx.x, wave = t >> 6, lane = t & 63;
  const int row = blockIdx.x * 4 + wave;      // 0..32767
  const int b = row >> 12;
  const int i = row & (NPTS - 1);
  const float* xb  = x + (size_t)b * NPTS * 64;
  const float* sqb = sq + ((size_t)b << 12);
  const float sqi = sqb[i];

  float4 q[16];
#pragma unroll
  for (int c4 = 0; c4 < 16; ++c4)
    q[c4] = *(const float4*)(xb + (size_t)i * 64 + c4 * 4);

  const int n = gcnt[row];

  if (n <= CAP) {
    unsigned long long vk[3];
#pragma unroll
    for (int s = 0; s < 3; ++s) {
      int li = s * 64 + lane;
      unsigned long long v = 0xFFFFFFFFFFFULL;        // sentinel > any real
      if (li < n) {
        int j = glist[(size_t)row * CAP + li];
        const float4* xj = (const float4*)(xb + (size_t)j * 64);
        float dot = 0.f;
#pragma unroll
        for (int c4 = 0; c4 < 16; ++c4) {
          float4 c = xj[c4];
          dot = fmaf(q[c4].x, c.x, dot);
          dot = fmaf(q[c4].y, c.y, dot);
          dot = fmaf(q[c4].z, c.z, dot);
          dot = fmaf(q[c4].w, c.w, dot);
        }
        float d = fmaf(-2.f, dot, sqi + sqb[j]);
        unsigned u  = __float_as_uint(d);
        unsigned ck = (u & 0x80000000u) ? ~u : (u | 0x80000000u);
        v = ((unsigned long long)ck << 12) | (unsigned)j;
      }
      vk[s] = v;
    }
    // radix-select: prefix ends as the exact 32nd-smallest value (distinct)
    unsigned long long prefix = 0;
    int need = 32;
    for (int bit = 43; bit >= 0; --bit) {
      unsigned long long hm = (bit == 43) ? 0ULL
          : (~((1ULL << (bit + 1)) - 1ULL) & 0xFFFFFFFFFFFULL);
      int cnt0 = 0;
#pragma unroll
      for (int s = 0; s < 3; ++s) {
        bool a = ((vk[s] ^ prefix) & hm) == 0ULL;
        bool z = ((vk[s] >> bit) & 1ULL) == 0ULL;
        cnt0 += (int)__popcll(__ballot(a && z));
      }
      if (cnt0 < need) { need -= cnt0; prefix |= 1ULL << bit; }
    }
    int prev = 0;
#pragma unroll
    for (int s = 0; s < 3; ++s) {
      bool sel = vk[s] <= prefix;
      unsigned long long m = __ballot(sel);
      int rank = (int)__popcll(m & ((1ULL << lane) - 1ULL));
      if (sel)
        idx_out[(size_t)row * KNN + prev + rank] =
            (unsigned short)(vk[s] & 0xFFFULL);
      prev += (int)__popcll(m);
    }
  } else {
    // fallback: exact full scan, validated ballot-insert
    unsigned long long ent = (0xFFFFFFFFFFFULL << 5) | (unsigned long long)(lane & 31);
    unsigned long long M   = (0xFFFFFFFFFFFULL << 5) | 31ULL;
    for (int c0 = 0; c0 < NPTS; c0 += 64) {
      const int j = c0 + lane;
      const float4* xj = (const float4*)(xb + (size_t)j * 64);
      float dot = 0.f;
#pragma unroll
      for (int c4 = 0; c4 < 16; ++c4) {
        float4 c = xj[c4];
        dot = fmaf(q[c4].x, c.x, dot);
        dot = fmaf(q[c4].y, c.y, dot);
        dot = fmaf(q[c4].z, c.z, dot);
        dot = fmaf(q[c4].w, c.w, dot);
      }
      float d = fmaf(-2.f, dot, sqi + sqb[j]);
      unsigned u  = __float_as_uint(d);
      unsigned ck = (u & 0x80000000u) ? ~u : (u | 0x80000000u);
      unsigned long long cq = ((unsigned long long)ck << 12) | (unsigned)j;
      unsigned long long mask = __ballot(cq < (M >> 5));
      while (mask) {
        const int src = __builtin_ctzll(mask);
        mask &= mask - 1;
        const unsigned long long bq = shfl_u64(cq, src);
        if (bq < (M >> 5)) {
          const unsigned slot = (unsigned)(M & 31ULL);
          if ((unsigned)(lane & 31) == slot) ent = (bq << 5) | slot;
          unsigned long long v = ent;
#pragma unroll
          for (int off = 16; off >= 1; off >>= 1) {
            unsigned long long w2 = shfl_xor_u64(v, off);
            v = (v > w2) ? v : w2;
          }
          M = v;
        }
      }
    }
    if (lane < 32)
      idx_out[(size_t)row * KNN + lane] =
          (unsigned short)((ent >> 5) & 0xFFFULL);
  }
}

// ---------------- F=3 kNN (validated two-pass VALU path) ----------------
template <int F>
__global__ __launch_bounds__(256, 2) void knn_tiled(const float* __restrict__ x,
                                                    const float* __restrict__ sq,
                                                    unsigned short* __restrict__ idx_out) {
  constexpr int FP = 4;
  constexpr int TC = 256;
  constexpr int RPB = 32;
  constexpr int RPW = 8;

  __shared__ __attribute__((aligned(16))) float qv[RPB][FP];
  __shared__ float qsq[RPB];
  __shared__ __attribute__((aligned(16))) float ct[TC][FP];
  __shared__ float csq[TC];

  const int t    = threadIdx.x;
  const int wave = t >> 6;
  const int lane = t & 63;
  const int rowbase = blockIdx.x << 5;
  const int b     = rowbase >> 12;
  const int ibase = rowbase & (NPTS - 1);
  const float* xb  = x + (size_t)b * NPTS * F;
  const float* sqb = sq + (b << 12);

  if (t < RPB) {
    qv[t][0] = xb[(size_t)(ibase + t) * 3 + 0];
    qv[t][1] = xb[(size_t)(ibase + t) * 3 + 1];
    qv[t][2] = xb[(size_t)(ibase + t) * 3 + 2];
    qv[t][3] = 0.f;
    qsq[t] = sqb[ibase + t];
  }
  __syncthreads();

  const int r0 = wave << 3;
  float sqi[RPW];
#pragma unroll
  for (int rr = 0; rr < RPW; ++rr) sqi[rr] = qsq[r0 + rr];

  unsigned mn[RPW];
#pragma unroll
  for (int rr = 0; rr < RPW; ++rr) mn[rr] = 0xFFFFFFFFu;

  for (int tile = 0; tile < NPTS / TC; ++tile) {
    __syncthreads();
    {
      int jg = tile * TC + t;
      ct[t][0] = xb[(size_t)jg * 3 + 0];
      ct[t][1] = xb[(size_t)jg * 3 + 1];
      ct[t][2] = xb[(size_t)jg * 3 + 2];
      ct[t][3] = 0.f;
      csq[t] = sqb[jg];
    }
    __syncthreads();

    float4 c0 = *reinterpret_cast<const float4*>(&ct[lane][0]);
    float4 c1 = *reinterpret_cast<const float4*>(&ct[lane + 64][0]);
    float4 c2 = *reinterpret_cast<const float4*>(&ct[lane + 128][0]);
    float4 c3 = *reinterpret_cast<const float4*>(&ct[lane + 192][0]);
    float cs[4];
#pragma unroll
    for (int s = 0; s < 4; ++s) cs[s] = csq[lane + 64 * s];

#pragma unroll
    for (int rr = 0; rr < RPW; ++rr) {
      float4 q = *reinterpret_cast<const float4*>(&qv[r0 + rr][0]);
      float dd[4];
      dd[0] = fmaf(q.z, c0.z, fmaf(q.y, c0.y, q.x * c0.x));
      dd[1] = fmaf(q.z, c1.z, fmaf(q.y, c1.y, q.x * c1.x));
      dd[2] = fmaf(q.z, c2.z, fmaf(q.y, c2.y, q.x * c2.x));
      dd[3] = fmaf(q.z, c3.z, fmaf(q.y, c3.y, q.x * c3.x));
#pragma unroll
      for (int s = 0; s < 4; ++s) {
        float d = fmaf(-2.f, dd[s], sqi[rr] + cs[s]);
        unsigned u  = __float_as_uint(d);
        unsigned ck = (u & 0x80000000u) ? ~u : (u | 0x80000000u);
        mn[rr] = ck < mn[rr] ? ck : mn[rr];
      }
    }
  }

  unsigned tau[RPW];
#pragma unroll
  for (int rr = 0; rr < RPW; ++rr) {
    const unsigned v = mn[rr];
    unsigned prefix = 0;
    int need = 32;
    int act = 1;
    for (int bit = 31; bit >= 0; --bit) {
      const unsigned bv = (v >> bit) & 1u;
      unsigned long long m0 = __ballot(act && (bv == 0u));
      int c0n = (int)__popcll(m0);
      if (c0n >= need) {
        act = act && (bv == 0u);
      } else {
        need -= c0n;
        act = act && (bv == 1u);
        prefix |= (1u << bit);
      }
    }
    tau[rr] = prefix;
  }

  unsigned long long ent[RPW], M[RPW];
#pragma unroll
  for (int rr = 0; rr < RPW; ++rr) {
    ent[rr] = (0xFFFFFFFFFFFULL << 5) | (unsigned long long)(lane & 31);
    M[rr]   = (0xFFFFFFFFFFFULL << 5) | 31ULL;
  }

  for (int tile = 0; tile < NPTS / TC; ++tile) {
    __syncthreads();
    {
      int jg = tile * TC + t;
      ct[t][0] = xb[(size_t)jg * 3 + 0];
      ct[t][1] = xb[(size_t)jg * 3 + 1];
      ct[t][2] = xb[(size_t)jg * 3 + 2];
      ct[t][3] = 0.f;
      csq[t] = sqb[jg];
    }
    __syncthreads();

    float4 c0 = *reinterpret_cast<const float4*>(&ct[lane][0]);
    float4 c1 = *reinterpret_cast<const float4*>(&ct[lane + 64][0]);
    float4 c2 = *reinterpret_cast<const float4*>(&ct[lane + 128][0]);
    float4 c3 = *reinterpret_cast<const float4*>(&ct[lane + 192][0]);
    float cs[4];
#pragma unroll
    for (int s = 0; s < 4; ++s) cs[s] = csq[lane + 64 * s];

#pragma unroll
    for (int rr = 0; rr < RPW; ++rr) {
      float4 q = *reinterpret_cast<const float4*>(&qv[r0 + rr][0]);
      float dd[4];
      dd[0] = fmaf(q.z, c0.z, fmaf(q.y, c0.y, q.x * c0.x));
      dd[1] = fmaf(q.z, c1.z, fmaf(q.y, c1.y, q.x * c1.x));
      dd[2] = fmaf(q.z, c2.z, fmaf(q.y, c2.y, q.x * c2.x));
      dd[3] = fmaf(q.z, c3.z, fmaf(q.y, c3.y, q.x * c3.x));
#pragma unroll
      for (int s = 0; s < 4; ++s) {
        float d = fmaf(-2.f, dd[s], sqi[rr] + cs[s]);
        unsigned u  = __float_as_uint(d);
        unsigned ck = (u & 0x80000000u) ? ~u : (u | 0x80000000u);
        unsigned long long mask = __ballot(ck <= tau[rr]);
        while (mask) {
          const int src = __builtin_ctzll(mask);
          mask &= mask - 1;
          const unsigned bk   = (unsigned)__shfl((int)ck, src, 64);
          const unsigned bidx = (unsigned)(tile * TC + s * 64 + src);
          const unsigned long long bq = ((unsigned long long)bk << 12) | bidx;
          if (bq < (M[rr] >> 5)) {
            const unsigned slot = (unsigned)(M[rr] & 31ULL);
            if ((unsigned)(lane & 31) == slot)
              ent[rr] = (bq << 5) | slot;
            unsigned long long v = ent[rr];
#pragma unroll
            for (int off = 16; off >= 1; off >>= 1) {
              unsigned long long w2 = shfl_xor_u64(v, off);
              v = (v > w2) ? v : w2;
            }
            M[rr] = v;
          }
        }
      }
    }
  }

  if (lane < 32) {
#pragma unroll
    for (int rr = 0; rr < RPW; ++rr)
      idx_out[((rowbase + r0 + rr) << 5) + lane] =
          (unsigned short)((ent[rr] >> 5) & 0xFFFULL);
  }
}

// ---------------- per-node P = x.Wbot ; C = x.(Wtop-Wbot) + b ----------------
__global__ __launch_bounds__(256) void mlp_pc_kernel(const float* __restrict__ xin,
                                                     const float* __restrict__ W,
                                                     const float* __restrict__ bias,
                                                     float* __restrict__ P,
                                                     float* C,
                                                     int F, int O, int total) {
  int t = blockIdx.x * 256 + threadIdx.x;
  if (t >= total) return;
  int n = t / O, o = t % O;
  const float* xr = xin + (size_t)n * F;
  const float* Wt = W + o;
  const float* Wb = W + (size_t)F * O + o;
  float p = 0.f, c = 0.f;
  for (int f = 0; f < F; ++f) {
    float a  = xr[f];
    float wt = Wt[(size_t)f * O];
    float wb = Wb[(size_t)f * O];
    p = fmaf(a, wb, p);
    c = fmaf(a, wt - wb, c);
  }
  P[t] = p;
  C[t] = c + bias[o];
}

// ---------------- h[t] (pre-filled with C) += max_k P[idx_k] ----------------
__global__ __launch_bounds__(256) void aggregate_kernel(const unsigned short* __restrict__ idx,
                                                        const float* __restrict__ P,
                                                        float* h, int O, int total) {
  int t = blockIdx.x * 256 + threadIdx.x;
  if (t >= total) return;
  int n = t / O, o = t % O;
  const unsigned short* ix = idx + (size_t)n * KNN;
  const int rowbase = (n >> 12) << 12;
  float m = -3.402823466e+38f;
  for (int k = 0; k < KNN; ++k) {
    int jg = rowbase + ix[k];
    float v = P[(size_t)jg * O + o];
    m = fmaxf(m, v);
  }
  h[t] = h[t] + m;
}

// ---------------- BN stats over relu(h): mean + invstd per channel ----------
__global__ __launch_bounds__(256) void bn_stats_kernel(const float* __restrict__ h,
                                                       float* __restrict__ stats) {
  const int c = blockIdx.x;
  const int t = threadIdx.x;
  double s = 0.0, s2 = 0.0;
  for (int n = t; n < NROWS; n += 256) {
    float v = h[(size_t)n * 64 + c];
    v = v > 0.f ? v : 0.f;
    s += v;
    s2 += (double)v * v;
  }
  __shared__ double ls[256], ls2[256];
  ls[t] = s; ls2[t] = s2;
  __syncthreads();
  for (int st = 128; st; st >>= 1) {
    if (t < st) { ls[t] += ls[t + st]; ls2[t] += ls2[t + st]; }
    __syncthreads();
  }
  if (t == 0) {
    double mean = ls[0] / (double)NROWS;
    double var  = ls2[0] / (double)NROWS - mean * mean;
    stats[c]      = (float)mean;
    stats[64 + c] = (float)(1.0 / sqrt(var + 1e-5));
  }
}

// ---------------- apply: out = (relu(h)-mean)*invstd*g + be ----------------
__global__ __launch_bounds__(256) void bn_apply_kernel(const float* h,
                                                       const float* __restrict__ stats,
                                                       const float* __restrict__ g,
                                                       const float* __restrict__ be,
                                                       float* out, int total) {
  int t = blockIdx.x * 256 + threadIdx.x;
  if (t >= total) return;
  int ch = t & 63;
  float v = fmaxf(h[t], 0.f);
  out[t] = (v - stats[ch]) * stats[64 + ch] * g[ch] + be[ch];
}

// ---------------- write h3 to out + per-block loss partials ----------------
__global__ __launch_bounds__(256) void final_kernel(const float* __restrict__ h3,
                                                    const float* __restrict__ target,
                                                    float* __restrict__ out,
                                                    double* __restrict__ partial) {
  double s = 0.0;
  for (int t = blockIdx.x * 256 + threadIdx.x; t < NROWS * 3; t += 256 * 256) {
    float v = h3[t];
    out[t] = v;
    float d = v - target[t];
    s += (double)d * d;
  }
  __shared__ double ls[256];
  int t = threadIdx.x;
  ls[t] = s;
  __syncthreads();
  for (int st = 128; st; st >>= 1) {
    if (t < st) ls[t] += ls[t + st];
    __syncthreads();
  }
  if (t == 0) partial[blockIdx.x] = ls[0];
}

__global__ __launch_bounds__(256) void loss_kernel(const double* __restrict__ partial,
                                                   float* __restrict__ out) {
  int t = threadIdx.x;
  __shared__ double ls[256];
  ls[t] = partial[t];
  __syncthreads();
  for (int st = 128; st; st >>= 1) {
    if (t < st) ls[t] += ls[t + st];
    __syncthreads();
  }
  if (t == 0) out[NROWS * 3] = (float)(ls[0] / (double)(NROWS * 3));
}

// ---------------- driver ----------------
extern "C" void kernel_launch(void* const* d_in, const int* in_sizes, int n_in,
                              void* d_out, int out_size, void* d_ws, size_t ws_size,
                              hipStream_t stream) {
  const float* x   = (const float*)d_in[0];
  const float* tgt = (const float*)d_in[1];
  const float* W1  = (const float*)d_in[2];
  const float* b1  = (const float*)d_in[3];
  const float* g1  = (const float*)d_in[4];
  const float* be1 = (const float*)d_in[5];
  const float* W2  = (const float*)d_in[6];
  const float* b2  = (const float*)d_in[7];
  const float* g2  = (const float*)d_in[8];
  const float* be2 = (const float*)d_in[9];
  const float* W3  = (const float*)d_in[10];
  const float* b3  = (const float*)d_in[11];
  float* out = (float*)d_out;

  char* ws = (char*)d_ws;
  size_t off = 0;
  float* sq    = (float*)(ws + off); off += (size_t)NROWS * 4;           // 128 KB
  unsigned short* idxb = (unsigned short*)(ws + off); off += (size_t)NROWS * KNN * 2; // 2 MB
  float* P     = (float*)(ws + off); off += (size_t)NROWS * 64 * 4;      // 8 MB
  float* CA    = (float*)(ws + off); off += (size_t)NROWS * 64 * 4;      // 8 MB
  float* CB    = (float*)(ws + off); off += (size_t)NROWS * 64 * 4;      // 8 MB
  int*   gcnt  = (int*)(ws + off);   off += (size_t)NROWS * 4;           // 128 KB
  unsigned short* glist = (unsigned short*)(ws + off); off += (size_t)NROWS * CAP * 2; // 12.6 MB
  float* stats = (float*)(ws + off); off += 256 * 4;
  float* sqmax = (float*)(ws + off); off += 64;
  double* part = (double*)(ws + off); off += 256 * 8;

  // hi/lo (bf16, 4 MB each) alias P (8 MB): P is dead during screen/rerank.
  unsigned short* hib = (unsigned short*)P;
  unsigned short* lob = hib + (size_t)NROWS * 64;

  const int T64 = NROWS * 64;
  const int T3  = NROWS * 3;

  // ---- layer 1 (F=3 -> 64), VALU kNN ----
  sqnorm_kernel<<<NROWS / 256, 256, 0, stream>>>(x, sq, 3);
  knn_tiled<3><<<NROWS / 32, 256, 0, stream>>>(x, sq, idxb);
  mlp_pc_kernel<<<T64 / 256, 256, 0, stream>>>(x, W1, b1, P, CA, 3, 64, T64);
  aggregate_kernel<<<T64 / 256, 256, 0, stream>>>(idxb, P, CA, 64, T64);
  bn_stats_kernel<<<64, 256, 0, stream>>>(CA, stats);
  bn_apply_kernel<<<T64 / 256, 256, 0, stream>>>(CA, stats, g1, be1, CA, T64);

  // ---- layer 2 (F=64 -> 64), MFMA screen + exact rerank ----
  sqnorm_kernel<<<NROWS / 256, 256, 0, stream>>>(CA, sq, 64);
  split_kernel<<<T64 / 256, 256, 0, stream>>>(CA, hib, lob, T64);
  batchmax_kernel<<<NB, 256, 0, stream>>>(sq, sqmax);
  knn_screen<<<512, 256, 0, stream>>>(hib, lob, sq, sqmax, gcnt, glist);
  knn_rerank<<<NROWS / 4, 256, 0, stream>>>(CA, sq, gcnt, glist, idxb);
  mlp_pc_kernel<<<T64 / 256, 256, 0, stream>>>(CA, W2, b2, P, CB, 64, 64, T64);
  aggregate_kernel<<<T64 / 256, 256, 0, stream>>>(idxb, P, CB, 64, T64);
  bn_stats_kernel<<<64, 256, 0, stream>>>(CB, stats);
  bn_apply_kernel<<<T64 / 256, 256, 0, stream>>>(CB, stats, g2, be2, CB, T64);

  // ---- layer 3 (F=64 -> 3), MFMA screen + exact rerank ----
  sqnorm_kernel<<<NROWS / 256, 256, 0, stream>>>(CB, sq, 64);
  split_kernel<<<T64 / 256, 256, 0, stream>>>(CB, hib, lob, T64);
  batchmax_kernel<<<NB, 256, 0, stream>>>(sq, sqmax);
  knn_screen<<<512, 256, 0, stream>>>(hib, lob, sq, sqmax, gcnt, glist);
  knn_rerank<<<NROWS / 4, 256, 0, stream>>>(CB, sq, gcnt, glist, idxb);
  mlp_pc_kernel<<<T3 / 256, 256, 0, stream>>>(CB, W3, b3, P, CA, 64, 3, T3);
  aggregate_kernel<<<T3 / 256, 256, 0, stream>>>(idxb, P, CA, 3, T3);

  // ---- output + loss ----
  final_kernel<<<256, 256, 0, stream>>>(CA, tgt, out, part);
  loss_kernel<<<1, 256, 0, stream>>>(part, out);
}